// Round 21
// baseline (529.404 us; speedup 1.0000x reference)
//
#include <hip/hip_runtime.h>
#include <stdint.h>
#include <stddef.h>

// Problem constants (reference: NB=4, B=16, C=256, L=4096)
#define NBR 4
#define BSZ 16
#define CHN 256
#define LEN 4096
#define NB_B 64            // NBR*BSZ
#define BL   65536         // BSZ*LEN
#define BN_EPS 1e-5f
#define W_EL (NBR*CHN*CHN) // 262144 elements per weight tensor
#define LT   128           // l-tile (round-7 value: the only L2-clean shape)

typedef unsigned short ushortT;
typedef unsigned short ushort4_t __attribute__((ext_vector_type(4)));
typedef unsigned short ushort8_t __attribute__((ext_vector_type(8)));
typedef short bf16x8 __attribute__((ext_vector_type(8)));
typedef _Float16 half8_t __attribute__((ext_vector_type(8)));
typedef float f32x4 __attribute__((ext_vector_type(4)));

__device__ __forceinline__ float bf2f(ushortT u) {
    return __uint_as_float(((unsigned)u) << 16);
}
__device__ __forceinline__ ushortT f2bf(float f) {
    unsigned b = __float_as_uint(f);
    return (ushortT)((b + 0x7FFFu + ((b >> 16) & 1u)) >> 16);
}
__device__ __forceinline__ ushortT f2h(float f) {
    _Float16 h = (_Float16)f;
    return *(ushortT*)&h;
}
// order-preserving float->uint encoding (monotone); memset-0 init is below enc(-inf)
__device__ __forceinline__ unsigned encf(float f) {
    unsigned b = __float_as_uint(f);
    return (b & 0x80000000u) ? ~b : (b | 0x80000000u);
}
__device__ __forceinline__ float decf(unsigned u) {
    unsigned b = (u & 0x80000000u) ? (u ^ 0x80000000u) : ~u;
    return __uint_as_float(b);
}

// LDS swizzle for sX (byte offsets). Rows are 512B (256 c elements). row 0..127.
__device__ __forceinline__ int swzX(int row, int cb) {
    return row * 512 + (cb ^ ((row & 7) << 4) ^ (((row >> 3) & 3) << 7));
}

// Stage x-tile [l=128][c=256] into LDS (bf16), transposed+converted, swizzled.
// Loads are coalesced per wave-instruction (lane -> l).
__device__ __forceinline__ void stage_x_f32(const float* x, ushortT* sX, int z, int lbase, int tid)
{
    const int ls = tid & 127;
    const int gh = tid >> 7;
    const float* xp = x + (size_t)z * CHN * LEN + lbase + ls;
#pragma unroll
    for (int g = 0; g < 16; ++g) {
        int c0 = (gh * 16 + g) * 8;
        ushort8_t u;
#pragma unroll
        for (int i = 0; i < 8; ++i) u[i] = f2bf(xp[(size_t)(c0 + i) * LEN]);
        *(ushort8_t*)((char*)sX + swzX(ls, c0 * 2)) = u;
    }
}

// Fused-agg staging, round-21: v is F16, the 4-way weighted combine runs as
// 8-wide _Float16 vector FMAs (clang -> v_pk_fma_f16): ~16 packed ops per
// 8 elems vs ~88 scalar ops in the bf16 form — ogemm was VALU-bound on this
// combine (staging VALU ~11k cyc/wave vs ~5k MFMA). LDS writes keep the
// round-15 conflict-free scratch transpose. agg lands in sX as f16.
__device__ __forceinline__ void stage_agg(const ushortT* v, ushortT* sX, ushortT* sT,
                                          const float aj[4], int b_, int lbase, int tid)
{
    const int lane = tid & 63;
    const int wave = tid >> 6;
    const int c4   = lane >> 4;        // 0..3: c within the wave's 4-c group
    const int lg   = lane & 15;        // l-octet
    ushortT* tw = sT + wave * 528;     // 1056B per wave, rows padded to 264B
    const ushortT* vb0 = v + (size_t)(0 * BSZ + b_) * CHN * LEN;
    const ushortT* vb1 = v + (size_t)(1 * BSZ + b_) * CHN * LEN;
    const ushortT* vb2 = v + (size_t)(2 * BSZ + b_) * CHN * LEN;
    const ushortT* vb3 = v + (size_t)(3 * BSZ + b_) * CHN * LEN;
    const _Float16 h0 = (_Float16)aj[0], h1 = (_Float16)aj[1],
                   h2 = (_Float16)aj[2], h3 = (_Float16)aj[3];
    const half8_t a0 = {h0,h0,h0,h0,h0,h0,h0,h0};
    const half8_t a1 = {h1,h1,h1,h1,h1,h1,h1,h1};
    const half8_t a2 = {h2,h2,h2,h2,h2,h2,h2,h2};
    const half8_t a3 = {h3,h3,h3,h3,h3,h3,h3,h3};
#pragma unroll 2
    for (int pass = 0; pass < 16; ++pass) {
        const int c = pass * 16 + wave * 4 + c4;
        const size_t base = (size_t)c * LEN + lbase + lg * 8;
        half8_t r0 = *(const half8_t*)(vb0 + base);
        half8_t r1 = *(const half8_t*)(vb1 + base);
        half8_t r2 = *(const half8_t*)(vb2 + base);
        half8_t r3 = *(const half8_t*)(vb3 + base);
        half8_t s = a0 * r0 + a1 * r1 + a2 * r2 + a3 * r3;
        *(half8_t*)(tw + c4 * 132 + lg * 8) = s;        // l-contiguous scratch write

        const int cb = pass * 32 + wave * 8;             // byte offset of 4-c group
#pragma unroll
        for (int sub = 0; sub < 2; ++sub) {
            const int row = sub * 64 + lane;             // 0..127
            ushort4_t t;
#pragma unroll
            for (int cc = 0; cc < 4; ++cc) t[cc] = tw[cc * 132 + row];
            *(ushort4_t*)((char*)sX + swzX(row, cb)) = t;
        }
    }
}

// One K-chunk (64 c) of MFMA — round-16 form (4x4 acc, the 128-VGPR-cliff
// safe shape). F16 variant switches the intrinsic (fragment layouts are
// dtype-independent on gfx950). W fragments in PRE-PACKED order
// Wb2[ob][cb][lane][8] -> base + lane*16B = coalesced 1KB dwordx4 (L2).
// A = activations (M=l) from LDS, B = W (N=o). acc[mf][nf] row=l col=o.
template <bool F16>
__device__ __forceinline__ void mfma_chunk_frag(const ushortT* sX, const ushortT* __restrict__ Wb2,
                                                int otile, f32x4 acc[4][4],
                                                int wr, int wc, int lane, int kb)
{
    const int am = wr * 64 + (lane & 15);
    const int kg = (lane >> 4) * 16;   // byte offset of this lane's k-group (LDS)
#pragma unroll
    for (int s = 0; s < 2; ++s) {
        const int cb = kb * 2 + s;
        bf16x8 a[4], b[4];
#pragma unroll
        for (int nf = 0; nf < 4; ++nf) {
            const int ob = otile * 8 + wc * 4 + nf;
            b[nf] = *(const bf16x8*)(Wb2 + (((size_t)ob * 8 + cb) * 64 + lane) * 8);
        }
#pragma unroll
        for (int mf = 0; mf < 4; ++mf)
            a[mf] = *(const bf16x8*)((const char*)sX + swzX(am + mf * 16, kb * 128 + s * 64 + kg));
#pragma unroll
        for (int mf = 0; mf < 4; ++mf)
#pragma unroll
            for (int nf = 0; nf < 4; ++nf) {
                if (!F16)
                    acc[mf][nf] = __builtin_amdgcn_mfma_f32_16x16x32_bf16(a[mf], b[nf], acc[mf][nf], 0, 0, 0);
                else
                    acc[mf][nf] = __builtin_amdgcn_mfma_f32_16x16x32_f16(
                        *(half8_t*)&a[mf], *(half8_t*)&b[nf], acc[mf][nf], 0, 0, 0);
            }
    }
}

// ---------------------------------------------------------------------------
// QKV fused (round-16 structure): stage x-tile once (ONE barrier), then 6
// barrier-free GEMM-tiles with coalesced fragment-order W loads.
// Wq/Wk epilogue: per-o sum & max over l -> atomics.
// Wv epilogue: bias + F16 store (round-21: f16 > bf16 precision for O(1) v,
// and enables packed-f16 aggregation in ogemm) to vbuf[z][c][l].
// ---------------------------------------------------------------------------
__global__ __launch_bounds__(256, 2)
void qkv_kernel(const float* __restrict__ x, const ushortT* __restrict__ Wbf,
                const float* __restrict__ bv,
                float* __restrict__ qsum, unsigned* __restrict__ qmax,
                float* __restrict__ ksum, unsigned* __restrict__ kmax,
                ushortT* __restrict__ vbuf)
{
    __shared__ ushortT sX[LT * 256];    // 64 KiB (only LDS)
    const int tid = threadIdx.x;
    const int lane = tid & 63;
    const int wv = tid >> 6;
    const int wr = wv >> 1, wc = wv & 1;
    const int lbase = blockIdx.x * LT;
    const int z = blockIdx.y;
    const int n = z >> 4;

    stage_x_f32(x, sX, z, lbase, tid);
    __syncthreads();                    // the only barrier

    const f32x4 z4 = {0.f, 0.f, 0.f, 0.f};

    for (int w = 0; w < 3; ++w) {
        const ushortT* Wb2 = Wbf + ((size_t)w * NBR + n) * CHN * CHN;
        for (int ot = 0; ot < 2; ++ot) {
            f32x4 acc[4][4];
#pragma unroll
            for (int mf = 0; mf < 4; ++mf)
#pragma unroll
                for (int nf = 0; nf < 4; ++nf) acc[mf][nf] = z4;
#pragma unroll
            for (int kb = 0; kb < 4; ++kb)
                mfma_chunk_frag<false>(sX, Wb2, ot, acc, wr, wc, lane, kb);

            const int obase = ot * 128;
            if (w < 2) {
                float* rs = (w == 0) ? qsum : ksum;
                unsigned* rm = (w == 0) ? qmax : kmax;
#pragma unroll
                for (int nf = 0; nf < 4; ++nf) {
                    float s = 0.f, m = -3.4e38f;
#pragma unroll
                    for (int mf = 0; mf < 4; ++mf)
#pragma unroll
                        for (int r = 0; r < 4; ++r) {
                            float v = acc[mf][nf][r];
                            s += v; m = fmaxf(m, v);
                        }
                    s += __shfl_xor(s, 16); s += __shfl_xor(s, 32);
                    m = fmaxf(m, __shfl_xor(m, 16)); m = fmaxf(m, __shfl_xor(m, 32));
                    if (lane < 16) {
                        int o = obase + wc * 64 + nf * 16 + lane;
                        atomicAdd(&rs[z * CHN + o], s);
                        atomicMax(&rm[z * CHN + o], encf(m));
                    }
                }
            } else {
#pragma unroll
                for (int nf = 0; nf < 4; ++nf) {
                    int o = obase + wc * 64 + nf * 16 + (lane & 15);
                    float bvv = bv[n * CHN + o];
#pragma unroll
                    for (int mf = 0; mf < 4; ++mf) {
                        int l = lbase + wr * 64 + mf * 16 + ((lane >> 4) << 2);
                        ushort4_t u;
#pragma unroll
                        for (int r = 0; r < 4; ++r) u[r] = f2h(acc[mf][nf][r] + bvv);
                        *(ushort4_t*)(vbuf + (size_t)(z * CHN + o) * LEN + l) = u;
                    }
                }
            }
        }
    }
}

// ---------------------------------------------------------------------------
// O GEMM, 4-branch merged (round-16 structure): one block per (l-tile, b_)
// loops the 4 output branches; v HBM-fetched once, L2/L3-hit for i>=1.
// Round-21: packed-f16 aggregation staging + f16 MFMA (Wo packed as f16).
// Per branch: stage_agg -> barrier -> GEMM -> epilogue -> barrier.
// ---------------------------------------------------------------------------
__global__ __launch_bounds__(256, 2)
void ogemm_kernel(const ushortT* __restrict__ v, const ushortT* __restrict__ Wbo,
                  const float* __restrict__ attn, const float* __restrict__ bo_,
                  float* __restrict__ bnsum, float* __restrict__ bnss,
                  ushortT* __restrict__ outpre)
{
    __shared__ ushortT sX[LT * 256];    // 64 KiB
    __shared__ ushortT sT[4 * 528];     // 4.2 KiB wave-private transpose scratch
    const int tid = threadIdx.x;
    const int lane = tid & 63;
    const int wv = tid >> 6;
    const int wr = wv >> 1, wc = wv & 1;
    const int lbase = blockIdx.x * LT;
    const int b_ = blockIdx.y;          // 0..15
    const f32x4 z4 = {0.f, 0.f, 0.f, 0.f};

    for (int i = 0; i < NBR; ++i) {     // output branch
        const int z = i * BSZ + b_;
        const ushortT* Wb2 = Wbo + (size_t)i * CHN * CHN;

        float aj[4];
#pragma unroll
        for (int j = 0; j < 4; ++j) aj[j] = attn[(i * 4 + j) * BSZ + b_];

        if (i) __syncthreads();         // previous GEMM done reading sX
        stage_agg(v, sX, sT, aj, b_, lbase, tid);
        __syncthreads();                // sX ready

        for (int ot = 0; ot < 2; ++ot) {
            f32x4 acc[4][4];
#pragma unroll
            for (int mf = 0; mf < 4; ++mf)
#pragma unroll
                for (int nf = 0; nf < 4; ++nf) acc[mf][nf] = z4;
#pragma unroll
            for (int kb = 0; kb < 4; ++kb)
                mfma_chunk_frag<true>(sX, Wb2, ot, acc, wr, wc, lane, kb);

            const int obase = ot * 128;
#pragma unroll
            for (int nf = 0; nf < 4; ++nf) {
                int o = obase + wc * 64 + nf * 16 + (lane & 15);
                float bb = bo_[i * CHN + o];
                float s = 0.f, q2 = 0.f;
#pragma unroll
                for (int mf = 0; mf < 4; ++mf) {
                    int l = lbase + wr * 64 + mf * 16 + ((lane >> 4) << 2);
                    ushort4_t u;
#pragma unroll
                    for (int r = 0; r < 4; ++r) {
                        float vv = acc[mf][nf][r] + bb;
                        u[r] = f2bf(vv);
                        s += vv; q2 += vv * vv;
                    }
                    *(ushort4_t*)(outpre + (size_t)(z * CHN + o) * LEN + l) = u;
                }
                s += __shfl_xor(s, 16); s += __shfl_xor(s, 32);
                q2 += __shfl_xor(q2, 16); q2 += __shfl_xor(q2, 32);
                if (lane < 16) {
                    atomicAdd(&bnsum[i * CHN + o], s);
                    atomicAdd(&bnss[i * CHN + o], q2);
                }
            }
        }
    }
}

// convert all 4 weight tensors fp32 -> MFMA-FRAGMENT order:
// Wq/Wk/Wv as bf16, Wo as F16 (round-21: feeds the f16 ogemm).
// Wbf[w][n][ob][cb][lane][8], o = ob*16 + (lane&15), c = cb*32 + (lane>>4)*8 + j
__global__ void wcvt_kernel(const float* __restrict__ Wq, const float* __restrict__ Wk,
                            const float* __restrict__ Wv, const float* __restrict__ Wo,
                            ushortT* __restrict__ Wbf)
{
    int t = blockIdx.x * 256 + threadIdx.x;    // one thread per 8-elem fragment slice
    if (t < 4 * (W_EL / 8)) {
        const float* srcs[4] = {Wq, Wk, Wv, Wo};
        int w    = t >> 15;          // W_EL/8 = 32768 per tensor
        int r    = t & 32767;
        int lane = r & 63;
        int cb   = (r >> 6) & 7;
        int ob   = (r >> 9) & 15;
        int n    = r >> 13;
        const float* src = srcs[w] + (size_t)n * CHN * CHN;
        int o = ob * 16 + (lane & 15);
        int c = cb * 32 + (lane >> 4) * 8;
        float4 f0 = *(const float4*)(src + (size_t)o * CHN + c);
        float4 f1 = *(const float4*)(src + (size_t)o * CHN + c + 4);
        ushort8_t u;
        if (w == 3) {
            u[0]=f2h(f0.x); u[1]=f2h(f0.y); u[2]=f2h(f0.z); u[3]=f2h(f0.w);
            u[4]=f2h(f1.x); u[5]=f2h(f1.y); u[6]=f2h(f1.z); u[7]=f2h(f1.w);
        } else {
            u[0]=f2bf(f0.x); u[1]=f2bf(f0.y); u[2]=f2bf(f0.z); u[3]=f2bf(f0.w);
            u[4]=f2bf(f1.x); u[5]=f2bf(f1.y); u[6]=f2bf(f1.z); u[7]=f2bf(f1.w);
        }
        *(ushort8_t*)(Wbf + ((size_t)w * NBR + n) * CHN * CHN
                          + (((size_t)ob * 8 + cb) * 64 + lane) * 8) = u;
    }
}

// ---------------------------------------------------------------------------
// attention coefficients: scores[i,j,b] = (sum_c sq*sk) * edge_w[i,j] / 64
// attn[i,j,b] = softmax_j(scores) * softmax(branch_imp)[j]
// sq = qsum/L + dec(qmax) + 2*bq  (mean+max, bias shifts both by bq)
// ---------------------------------------------------------------------------
__global__ void attn_kernel(const float* __restrict__ qsum, const unsigned* __restrict__ qmax,
                            const float* __restrict__ ksum, const unsigned* __restrict__ kmax,
                            const float* __restrict__ bq, const float* __restrict__ bk,
                            const float* __restrict__ edge, const float* __restrict__ bimp,
                            float* __restrict__ attn)
{
    __shared__ float sc[NBR][NBR][BSZ];
    int tid = threadIdx.x;           // 256 threads == 4*4*16
    int i = tid >> 6, j = (tid >> 4) & 3, b = tid & 15;
    float s = 0.f;
    const float invL = 1.0f / (float)LEN;
    for (int c = 0; c < CHN; ++c) {
        int qi = (i * BSZ + b) * CHN + c;
        int ki = (j * BSZ + b) * CHN + c;
        float sq = qsum[qi] * invL + decf(qmax[qi]) + 2.f * bq[i * CHN + c];
        float sk = ksum[ki] * invL + decf(kmax[ki]) + 2.f * bk[j * CHN + c];
        s += sq * sk;
    }
    sc[i][j][b] = s * edge[i * 4 + j] * (1.0f / 64.0f);
    __syncthreads();
    if (tid < 64) {
        int ii = tid >> 4, bb = tid & 15;
        float m = -3.4e38f;
        for (int jj = 0; jj < 4; ++jj) m = fmaxf(m, sc[ii][jj][bb]);
        float e[4]; float sum = 0.f;
        for (int jj = 0; jj < 4; ++jj) { e[jj] = __expf(sc[ii][jj][bb] - m); sum += e[jj]; }
        float bm = fmaxf(fmaxf(bimp[0], bimp[1]), fmaxf(bimp[2], bimp[3]));
        float be[4]; float bs = 0.f;
        for (int jj = 0; jj < 4; ++jj) { be[jj] = __expf(bimp[jj] - bm); bs += be[jj]; }
        for (int jj = 0; jj < 4; ++jj)
            attn[(ii * 4 + jj) * BSZ + bb] = (e[jj] / sum) * (be[jj] / bs);
    }
}

// finalize BN affine: scale = gamma*rsqrt(var+eps), shift = beta - mean*scale
__global__ void bnfin_kernel(const float* __restrict__ bnsum, const float* __restrict__ bnss,
                             const float* __restrict__ gamma, const float* __restrict__ beta,
                             float* __restrict__ scl, float* __restrict__ shf)
{
    int t = blockIdx.x * blockDim.x + threadIdx.x;   // 0..1023 = n*256+c
    if (t < NBR * CHN) {
        const float inv = 1.0f / (float)BL;
        float mean = bnsum[t] * inv;
        float var = bnss[t] * inv - mean * mean;
        float rs = rsqrtf(var + BN_EPS);
        float s = gamma[t] * rs;
        scl[t] = s;
        shf[t] = beta[t] - mean * s;
    }
}

// out = relu(out_pre*scale + shift) + x
__global__ __launch_bounds__(256)
void final_kernel(const ushortT* __restrict__ outpre, const float* __restrict__ x,
                  const float* __restrict__ scl, const float* __restrict__ shf,
                  float* __restrict__ out)
{
    const long long U = (long long)NB_B * CHN * (LEN / 8);   // 8,388,608 units of 8
    for (long long u = (long long)blockIdx.x * blockDim.x + threadIdx.x; u < U;
         u += (long long)gridDim.x * blockDim.x) {
        int l0 = (int)(u & 511) * 8;
        int c  = (int)(u >> 9) & 255;
        int zz = (int)(u >> 17);          // n*16+b
        int n  = zz >> 4;
        size_t base = ((size_t)zz * CHN + c) * LEN + l0;
        ushort8_t op = *(const ushort8_t*)(outpre + base);
        float4 x0 = *(const float4*)(x + base);
        float4 x1 = *(const float4*)(x + base + 4);
        float sc = scl[n * CHN + c];
        float sh = shf[n * CHN + c];
        float xr[8] = {x0.x, x0.y, x0.z, x0.w, x1.x, x1.y, x1.z, x1.w};
        float res[8];
#pragma unroll
        for (int e = 0; e < 8; ++e) {
            float bn = bf2f(op[e]) * sc + sh;
            res[e] = fmaxf(bn, 0.f) + xr[e];
        }
        float4 o0 = {res[0], res[1], res[2], res[3]};
        float4 o1 = {res[4], res[5], res[6], res[7]};
        *(float4*)(out + base) = o0;
        *(float4*)(out + base + 4) = o1;
    }
}

extern "C" void kernel_launch(void* const* d_in, const int* in_sizes, int n_in,
                              void* d_out, int out_size, void* d_ws, size_t ws_size,
                              hipStream_t stream)
{
    const float* x     = (const float*)d_in[0];
    const float* Wq    = (const float*)d_in[1];
    const float* bq    = (const float*)d_in[2];
    const float* Wk    = (const float*)d_in[3];
    const float* bk    = (const float*)d_in[4];
    const float* Wv    = (const float*)d_in[5];
    const float* bv    = (const float*)d_in[6];
    const float* Wo    = (const float*)d_in[7];
    const float* bo    = (const float*)d_in[8];
    const float* gamma = (const float*)d_in[9];
    const float* beta  = (const float*)d_in[10];
    const float* edge  = (const float*)d_in[11];
    const float* bimp  = (const float*)d_in[12];

    char* ws = (char*)d_ws;
    const size_t P_BYTES = (size_t)NBR * BSZ * CHN * LEN * 2;   // 128 MiB (bf16)
    ushortT* outpre = (ushortT*)ws;          // out_pre staging (ws[0:128Mi])
    size_t off = P_BYTES;
    float*    qsum = (float*)(ws + off);    off += 65536;
    unsigned* qmax = (unsigned*)(ws + off); off += 65536;
    float*    ksum = (float*)(ws + off);    off += 65536;
    unsigned* kmax = (unsigned*)(ws + off); off += 65536;
    float*    attn = (float*)(ws + off);    off += 1024;
    float*    bnsum= (float*)(ws + off);    off += 4096;
    float*    bnss = (float*)(ws + off);    off += 4096;
    float*    scl  = (float*)(ws + off);    off += 4096;
    float*    shf  = (float*)(ws + off);    off += 4096;

    // zero the small accumulators (sum=0; max uses encoding where 0 < enc(-inf))
    hipMemsetAsync(ws + P_BYTES, 0, off - P_BYTES, stream);

    // d_out scratch (all dead before final_kernel rewrites d_out):
    //   [0, 128Mi):    v (F16, [z][c][l]) written by qkv, read by ogemm
    //   [128Mi, +2Mi): Wbf (bf16 / f16 weights, fragment order) written by wcvt
    ushortT* vbuf = (ushortT*)d_out;
    ushortT* Wbf  = (ushortT*)((char*)d_out + ((size_t)134217728));
    float*   outf = (float*)d_out;

    wcvt_kernel<<<(4 * (W_EL / 8) + 255) / 256, 256, 0, stream>>>(Wq, Wk, Wv, Wo, Wbf);

    dim3 gq(LEN / LT, NB_B);   // (32, 64)
    qkv_kernel<<<gq, 256, 0, stream>>>(x, Wbf, bv, qsum, qmax, ksum, kmax, vbuf);
    attn_kernel<<<1, 256, 0, stream>>>(qsum, qmax, ksum, kmax, bq, bk, edge, bimp, attn);
    dim3 go(LEN / LT, BSZ);    // (32, 16): 512 blocks, 4 branches per block
    ogemm_kernel<<<go, 256, 0, stream>>>(vbuf, Wbf + (size_t)3 * W_EL, attn, bo, bnsum, bnss, outpre);
    bnfin_kernel<<<4, 256, 0, stream>>>(bnsum, bnss, gamma, beta, scl, shf);
    final_kernel<<<8192, 256, 0, stream>>>(outpre, x, scl, shf, outf);
}

// Round 22
// 487.708 us; speedup vs baseline: 1.0855x; 1.0855x over previous
//
#include <hip/hip_runtime.h>
#include <stdint.h>
#include <stddef.h>

// Problem constants (reference: NB=4, B=16, C=256, L=4096)
#define NBR 4
#define BSZ 16
#define CHN 256
#define LEN 4096
#define NB_B 64            // NBR*BSZ
#define BL   65536         // BSZ*LEN
#define BN_EPS 1e-5f
#define W_EL (NBR*CHN*CHN) // 262144 elements per weight tensor
#define LT   128           // l-tile (round-7 value: the only L2-clean shape)

typedef unsigned short ushortT;
typedef unsigned short ushort4_t __attribute__((ext_vector_type(4)));
typedef unsigned short ushort8_t __attribute__((ext_vector_type(8)));
typedef short bf16x8 __attribute__((ext_vector_type(8)));
typedef float f32x4 __attribute__((ext_vector_type(4)));

__device__ __forceinline__ float bf2f(ushortT u) {
    return __uint_as_float(((unsigned)u) << 16);
}
__device__ __forceinline__ ushortT f2bf(float f) {
    unsigned b = __float_as_uint(f);
    return (ushortT)((b + 0x7FFFu + ((b >> 16) & 1u)) >> 16);
}
// order-preserving float->uint encoding (monotone); memset-0 init is below enc(-inf)
__device__ __forceinline__ unsigned encf(float f) {
    unsigned b = __float_as_uint(f);
    return (b & 0x80000000u) ? ~b : (b | 0x80000000u);
}
__device__ __forceinline__ float decf(unsigned u) {
    unsigned b = (u & 0x80000000u) ? (u ^ 0x80000000u) : ~u;
    return __uint_as_float(b);
}

// LDS swizzle for sX (byte offsets). Rows are 512B (256 c bf16). row in 0..127.
__device__ __forceinline__ int swzX(int row, int cb) {
    return row * 512 + (cb ^ ((row & 7) << 4) ^ (((row >> 3) & 3) << 7));
}

// Stage x-tile [l=128][c=256] into LDS, transposed+converted, swizzled.
// Loads are coalesced per wave-instruction (lane -> l).
__device__ __forceinline__ void stage_x_f32(const float* x, ushortT* sX, int z, int lbase, int tid)
{
    const int ls = tid & 127;
    const int gh = tid >> 7;
    const float* xp = x + (size_t)z * CHN * LEN + lbase + ls;
#pragma unroll
    for (int g = 0; g < 16; ++g) {
        int c0 = (gh * 16 + g) * 8;
        ushort8_t u;
#pragma unroll
        for (int i = 0; i < 8; ++i) u[i] = f2bf(xp[(size_t)(c0 + i) * LEN]);
        *(ushort8_t*)((char*)sX + swzX(ls, c0 * 2)) = u;
    }
}

// Fused-agg staging (round-15 form): vector global reads (16B along l,
// coalesced) + conflict-free LDS writes via a per-wave scratch transpose.
__device__ __forceinline__ void stage_agg(const ushortT* v, ushortT* sX, ushortT* sT,
                                          const float aj[4], int b_, int lbase, int tid)
{
    const int lane = tid & 63;
    const int wave = tid >> 6;
    const int c4   = lane >> 4;        // 0..3: c within the wave's 4-c group
    const int lg   = lane & 15;        // l-octet
    ushortT* tw = sT + wave * 528;     // 1056B per wave, rows padded to 264B
    const ushortT* vb0 = v + (size_t)(0 * BSZ + b_) * CHN * LEN;
    const ushortT* vb1 = v + (size_t)(1 * BSZ + b_) * CHN * LEN;
    const ushortT* vb2 = v + (size_t)(2 * BSZ + b_) * CHN * LEN;
    const ushortT* vb3 = v + (size_t)(3 * BSZ + b_) * CHN * LEN;
#pragma unroll 2
    for (int pass = 0; pass < 16; ++pass) {
        const int c = pass * 16 + wave * 4 + c4;
        const size_t base = (size_t)c * LEN + lbase + lg * 8;
        ushort8_t r0 = *(const ushort8_t*)(vb0 + base);
        ushort8_t r1 = *(const ushort8_t*)(vb1 + base);
        ushort8_t r2 = *(const ushort8_t*)(vb2 + base);
        ushort8_t r3 = *(const ushort8_t*)(vb3 + base);
        ushort8_t u;
#pragma unroll
        for (int e = 0; e < 8; ++e) {
            float s = aj[0] * bf2f(r0[e]) + aj[1] * bf2f(r1[e])
                    + aj[2] * bf2f(r2[e]) + aj[3] * bf2f(r3[e]);
            u[e] = f2bf(s);
        }
        *(ushort8_t*)(tw + c4 * 132 + lg * 8) = u;      // l-contiguous scratch write

        const int cb = pass * 32 + wave * 8;             // byte offset of 4-c group
#pragma unroll
        for (int sub = 0; sub < 2; ++sub) {
            const int row = sub * 64 + lane;             // 0..127
            ushort4_t t;
#pragma unroll
            for (int cc = 0; cc < 4; ++cc) t[cc] = tw[cc * 132 + row];
            *(ushort4_t*)((char*)sX + swzX(row, cb)) = t;
        }
    }
}

// One K-chunk (64 c) of MFMA — round-7/16 form (4x4 acc, the 128-VGPR-cliff
// safe shape), NO setprio (round-19 A/B: setprio cost −10% here, matching
// the catalog's m190 GEMM-null). Compiler schedules the loads (m141 lesson).
// W B-fragments from global in PRE-PACKED fragment order Wb2[ob][cb][lane][8]
// -> base + lane*16B = one fully-coalesced 1KB dwordx4 per wave (L2-resident).
// A = x (M=l) from LDS, B = W (N=o). acc[mf][nf] row=l col=o.
__device__ __forceinline__ void mfma_chunk_frag(const ushortT* sX, const ushortT* __restrict__ Wb2,
                                                int otile, f32x4 acc[4][4],
                                                int wr, int wc, int lane, int kb)
{
    const int am = wr * 64 + (lane & 15);
    const int kg = (lane >> 4) * 16;   // byte offset of this lane's k-group (LDS)
#pragma unroll
    for (int s = 0; s < 2; ++s) {
        const int cb = kb * 2 + s;
        bf16x8 a[4], b[4];
#pragma unroll
        for (int nf = 0; nf < 4; ++nf) {
            const int ob = otile * 8 + wc * 4 + nf;
            b[nf] = *(const bf16x8*)(Wb2 + (((size_t)ob * 8 + cb) * 64 + lane) * 8);
        }
#pragma unroll
        for (int mf = 0; mf < 4; ++mf)
            a[mf] = *(const bf16x8*)((const char*)sX + swzX(am + mf * 16, kb * 128 + s * 64 + kg));
#pragma unroll
        for (int mf = 0; mf < 4; ++mf)
#pragma unroll
            for (int nf = 0; nf < 4; ++nf)
                acc[mf][nf] = __builtin_amdgcn_mfma_f32_16x16x32_bf16(a[mf], b[nf], acc[mf][nf], 0, 0, 0);
    }
}

// ---------------------------------------------------------------------------
// QKV fused (round-16 verbatim): stage x-tile once (ONE barrier), then 6
// barrier-free GEMM-tiles with coalesced fragment-order W loads.
// Wq/Wk epilogue: per-o sum & max over l -> atomics. Wv: bias + bf16 store
// to vbuf[z][c][l] (the write pattern measured at ~ideal WRITE_SIZE).
// ---------------------------------------------------------------------------
__global__ __launch_bounds__(256, 2)
void qkv_kernel(const float* __restrict__ x, const ushortT* __restrict__ Wbf,
                const float* __restrict__ bv,
                float* __restrict__ qsum, unsigned* __restrict__ qmax,
                float* __restrict__ ksum, unsigned* __restrict__ kmax,
                ushortT* __restrict__ vbuf)
{
    __shared__ ushortT sX[LT * 256];    // 64 KiB (only LDS)
    const int tid = threadIdx.x;
    const int lane = tid & 63;
    const int wv = tid >> 6;
    const int wr = wv >> 1, wc = wv & 1;
    const int lbase = blockIdx.x * LT;
    const int z = blockIdx.y;
    const int n = z >> 4;

    stage_x_f32(x, sX, z, lbase, tid);
    __syncthreads();                    // the only barrier

    const f32x4 z4 = {0.f, 0.f, 0.f, 0.f};

    for (int w = 0; w < 3; ++w) {
        const ushortT* Wb2 = Wbf + ((size_t)w * NBR + n) * CHN * CHN;
        for (int ot = 0; ot < 2; ++ot) {
            f32x4 acc[4][4];
#pragma unroll
            for (int mf = 0; mf < 4; ++mf)
#pragma unroll
                for (int nf = 0; nf < 4; ++nf) acc[mf][nf] = z4;
#pragma unroll
            for (int kb = 0; kb < 4; ++kb)
                mfma_chunk_frag(sX, Wb2, ot, acc, wr, wc, lane, kb);

            const int obase = ot * 128;
            if (w < 2) {
                float* rs = (w == 0) ? qsum : ksum;
                unsigned* rm = (w == 0) ? qmax : kmax;
#pragma unroll
                for (int nf = 0; nf < 4; ++nf) {
                    float s = 0.f, m = -3.4e38f;
#pragma unroll
                    for (int mf = 0; mf < 4; ++mf)
#pragma unroll
                        for (int r = 0; r < 4; ++r) {
                            float v = acc[mf][nf][r];
                            s += v; m = fmaxf(m, v);
                        }
                    s += __shfl_xor(s, 16); s += __shfl_xor(s, 32);
                    m = fmaxf(m, __shfl_xor(m, 16)); m = fmaxf(m, __shfl_xor(m, 32));
                    if (lane < 16) {
                        int o = obase + wc * 64 + nf * 16 + lane;
                        atomicAdd(&rs[z * CHN + o], s);
                        atomicMax(&rm[z * CHN + o], encf(m));
                    }
                }
            } else {
#pragma unroll
                for (int nf = 0; nf < 4; ++nf) {
                    int o = obase + wc * 64 + nf * 16 + (lane & 15);
                    float bvv = bv[n * CHN + o];
#pragma unroll
                    for (int mf = 0; mf < 4; ++mf) {
                        int l = lbase + wr * 64 + mf * 16 + ((lane >> 4) << 2);
                        ushort4_t u;
#pragma unroll
                        for (int r = 0; r < 4; ++r) u[r] = f2bf(acc[mf][nf][r] + bvv);
                        *(ushort4_t*)(vbuf + (size_t)(z * CHN + o) * LEN + l) = u;
                    }
                }
            }
        }
    }
}

// ---------------------------------------------------------------------------
// O GEMM, 4-branch merged (round-16 verbatim): one block per (l-tile, b_)
// loops the 4 output branches; v HBM-fetched once, L2/L3-hit for i>=1.
// Per branch: stage_agg -> barrier -> GEMM -> epilogue -> barrier.
// ---------------------------------------------------------------------------
__global__ __launch_bounds__(256, 2)
void ogemm_kernel(const ushortT* __restrict__ v, const ushortT* __restrict__ Wbo,
                  const float* __restrict__ attn, const float* __restrict__ bo_,
                  float* __restrict__ bnsum, float* __restrict__ bnss,
                  ushortT* __restrict__ outpre)
{
    __shared__ ushortT sX[LT * 256];    // 64 KiB
    __shared__ ushortT sT[4 * 528];     // 4.2 KiB wave-private transpose scratch
    const int tid = threadIdx.x;
    const int lane = tid & 63;
    const int wv = tid >> 6;
    const int wr = wv >> 1, wc = wv & 1;
    const int lbase = blockIdx.x * LT;
    const int b_ = blockIdx.y;          // 0..15
    const f32x4 z4 = {0.f, 0.f, 0.f, 0.f};

    for (int i = 0; i < NBR; ++i) {     // output branch
        const int z = i * BSZ + b_;
        const ushortT* Wb2 = Wbo + (size_t)i * CHN * CHN;

        float aj[4];
#pragma unroll
        for (int j = 0; j < 4; ++j) aj[j] = attn[(i * 4 + j) * BSZ + b_];

        if (i) __syncthreads();         // previous GEMM done reading sX
        stage_agg(v, sX, sT, aj, b_, lbase, tid);
        __syncthreads();                // sX ready

        for (int ot = 0; ot < 2; ++ot) {
            f32x4 acc[4][4];
#pragma unroll
            for (int mf = 0; mf < 4; ++mf)
#pragma unroll
                for (int nf = 0; nf < 4; ++nf) acc[mf][nf] = z4;
#pragma unroll
            for (int kb = 0; kb < 4; ++kb)
                mfma_chunk_frag(sX, Wb2, ot, acc, wr, wc, lane, kb);

            const int obase = ot * 128;
#pragma unroll
            for (int nf = 0; nf < 4; ++nf) {
                int o = obase + wc * 64 + nf * 16 + (lane & 15);
                float bb = bo_[i * CHN + o];
                float s = 0.f, q2 = 0.f;
#pragma unroll
                for (int mf = 0; mf < 4; ++mf) {
                    int l = lbase + wr * 64 + mf * 16 + ((lane >> 4) << 2);
                    ushort4_t u;
#pragma unroll
                    for (int r = 0; r < 4; ++r) {
                        float vv = acc[mf][nf][r] + bb;
                        u[r] = f2bf(vv);
                        s += vv; q2 += vv * vv;
                    }
                    *(ushort4_t*)(outpre + (size_t)(z * CHN + o) * LEN + l) = u;
                }
                s += __shfl_xor(s, 16); s += __shfl_xor(s, 32);
                q2 += __shfl_xor(q2, 16); q2 += __shfl_xor(q2, 32);
                if (lane < 16) {
                    atomicAdd(&bnsum[i * CHN + o], s);
                    atomicAdd(&bnss[i * CHN + o], q2);
                }
            }
        }
    }
}

// convert all 4 weight tensors fp32 -> bf16 in MFMA-FRAGMENT order:
// Wbf[w][n][ob][cb][lane][8] with o = ob*16 + (lane&15), c = cb*32 + (lane>>4)*8 + j
__global__ void wcvt_kernel(const float* __restrict__ Wq, const float* __restrict__ Wk,
                            const float* __restrict__ Wv, const float* __restrict__ Wo,
                            ushortT* __restrict__ Wbf)
{
    int t = blockIdx.x * 256 + threadIdx.x;    // one thread per 8-elem fragment slice
    if (t < 4 * (W_EL / 8)) {
        const float* srcs[4] = {Wq, Wk, Wv, Wo};
        int w    = t >> 15;          // W_EL/8 = 32768 per tensor
        int r    = t & 32767;
        int lane = r & 63;
        int cb   = (r >> 6) & 7;
        int ob   = (r >> 9) & 15;
        int n    = r >> 13;
        const float* src = srcs[w] + (size_t)n * CHN * CHN;
        int o = ob * 16 + (lane & 15);
        int c = cb * 32 + (lane >> 4) * 8;
        float4 f0 = *(const float4*)(src + (size_t)o * CHN + c);
        float4 f1 = *(const float4*)(src + (size_t)o * CHN + c + 4);
        ushort8_t u = {f2bf(f0.x), f2bf(f0.y), f2bf(f0.z), f2bf(f0.w),
                       f2bf(f1.x), f2bf(f1.y), f2bf(f1.z), f2bf(f1.w)};
        *(ushort8_t*)(Wbf + ((size_t)w * NBR + n) * CHN * CHN
                          + (((size_t)ob * 8 + cb) * 64 + lane) * 8) = u;
    }
}

// ---------------------------------------------------------------------------
// attention coefficients: scores[i,j,b] = (sum_c sq*sk) * edge_w[i,j] / 64
// attn[i,j,b] = softmax_j(scores) * softmax(branch_imp)[j]
// sq = qsum/L + dec(qmax) + 2*bq  (mean+max, bias shifts both by bq)
// ---------------------------------------------------------------------------
__global__ void attn_kernel(const float* __restrict__ qsum, const unsigned* __restrict__ qmax,
                            const float* __restrict__ ksum, const unsigned* __restrict__ kmax,
                            const float* __restrict__ bq, const float* __restrict__ bk,
                            const float* __restrict__ edge, const float* __restrict__ bimp,
                            float* __restrict__ attn)
{
    __shared__ float sc[NBR][NBR][BSZ];
    int tid = threadIdx.x;           // 256 threads == 4*4*16
    int i = tid >> 6, j = (tid >> 4) & 3, b = tid & 15;
    float s = 0.f;
    const float invL = 1.0f / (float)LEN;
    for (int c = 0; c < CHN; ++c) {
        int qi = (i * BSZ + b) * CHN + c;
        int ki = (j * BSZ + b) * CHN + c;
        float sq = qsum[qi] * invL + decf(qmax[qi]) + 2.f * bq[i * CHN + c];
        float sk = ksum[ki] * invL + decf(kmax[ki]) + 2.f * bk[j * CHN + c];
        s += sq * sk;
    }
    sc[i][j][b] = s * edge[i * 4 + j] * (1.0f / 64.0f);
    __syncthreads();
    if (tid < 64) {
        int ii = tid >> 4, bb = tid & 15;
        float m = -3.4e38f;
        for (int jj = 0; jj < 4; ++jj) m = fmaxf(m, sc[ii][jj][bb]);
        float e[4]; float sum = 0.f;
        for (int jj = 0; jj < 4; ++jj) { e[jj] = __expf(sc[ii][jj][bb] - m); sum += e[jj]; }
        float bm = fmaxf(fmaxf(bimp[0], bimp[1]), fmaxf(bimp[2], bimp[3]));
        float be[4]; float bs = 0.f;
        for (int jj = 0; jj < 4; ++jj) { be[jj] = __expf(bimp[jj] - bm); bs += be[jj]; }
        for (int jj = 0; jj < 4; ++jj)
            attn[(ii * 4 + jj) * BSZ + bb] = (e[jj] / sum) * (be[jj] / bs);
    }
}

// finalize BN affine: scale = gamma*rsqrt(var+eps), shift = beta - mean*scale
__global__ void bnfin_kernel(const float* __restrict__ bnsum, const float* __restrict__ bnss,
                             const float* __restrict__ gamma, const float* __restrict__ beta,
                             float* __restrict__ scl, float* __restrict__ shf)
{
    int t = blockIdx.x * blockDim.x + threadIdx.x;   // 0..1023 = n*256+c
    if (t < NBR * CHN) {
        const float inv = 1.0f / (float)BL;
        float mean = bnsum[t] * inv;
        float var = bnss[t] * inv - mean * mean;
        float rs = rsqrtf(var + BN_EPS);
        float s = gamma[t] * rs;
        scl[t] = s;
        shf[t] = beta[t] - mean * s;
    }
}

// out = relu(out_pre*scale + shift) + x
__global__ __launch_bounds__(256)
void final_kernel(const ushortT* __restrict__ outpre, const float* __restrict__ x,
                  const float* __restrict__ scl, const float* __restrict__ shf,
                  float* __restrict__ out)
{
    const long long U = (long long)NB_B * CHN * (LEN / 8);   // 8,388,608 units of 8
    for (long long u = (long long)blockIdx.x * blockDim.x + threadIdx.x; u < U;
         u += (long long)gridDim.x * blockDim.x) {
        int l0 = (int)(u & 511) * 8;
        int c  = (int)(u >> 9) & 255;
        int zz = (int)(u >> 17);          // n*16+b
        int n  = zz >> 4;
        size_t base = ((size_t)zz * CHN + c) * LEN + l0;
        ushort8_t op = *(const ushort8_t*)(outpre + base);
        float4 x0 = *(const float4*)(x + base);
        float4 x1 = *(const float4*)(x + base + 4);
        float sc = scl[n * CHN + c];
        float sh = shf[n * CHN + c];
        float xr[8] = {x0.x, x0.y, x0.z, x0.w, x1.x, x1.y, x1.z, x1.w};
        float res[8];
#pragma unroll
        for (int e = 0; e < 8; ++e) {
            float bn = bf2f(op[e]) * sc + sh;
            res[e] = fmaxf(bn, 0.f) + xr[e];
        }
        float4 o0 = {res[0], res[1], res[2], res[3]};
        float4 o1 = {res[4], res[5], res[6], res[7]};
        *(float4*)(out + base) = o0;
        *(float4*)(out + base + 4) = o1;
    }
}

extern "C" void kernel_launch(void* const* d_in, const int* in_sizes, int n_in,
                              void* d_out, int out_size, void* d_ws, size_t ws_size,
                              hipStream_t stream)
{
    const float* x     = (const float*)d_in[0];
    const float* Wq    = (const float*)d_in[1];
    const float* bq    = (const float*)d_in[2];
    const float* Wk    = (const float*)d_in[3];
    const float* bk    = (const float*)d_in[4];
    const float* Wv    = (const float*)d_in[5];
    const float* bv    = (const float*)d_in[6];
    const float* Wo    = (const float*)d_in[7];
    const float* bo    = (const float*)d_in[8];
    const float* gamma = (const float*)d_in[9];
    const float* beta  = (const float*)d_in[10];
    const float* edge  = (const float*)d_in[11];
    const float* bimp  = (const float*)d_in[12];

    char* ws = (char*)d_ws;
    const size_t P_BYTES = (size_t)NBR * BSZ * CHN * LEN * 2;   // 128 MiB (bf16)
    ushortT* outpre = (ushortT*)ws;          // out_pre staging (ws[0:128Mi])
    size_t off = P_BYTES;
    float*    qsum = (float*)(ws + off);    off += 65536;
    unsigned* qmax = (unsigned*)(ws + off); off += 65536;
    float*    ksum = (float*)(ws + off);    off += 65536;
    unsigned* kmax = (unsigned*)(ws + off); off += 65536;
    float*    attn = (float*)(ws + off);    off += 1024;
    float*    bnsum= (float*)(ws + off);    off += 4096;
    float*    bnss = (float*)(ws + off);    off += 4096;
    float*    scl  = (float*)(ws + off);    off += 4096;
    float*    shf  = (float*)(ws + off);    off += 4096;

    // zero the small accumulators (sum=0; max uses encoding where 0 < enc(-inf))
    hipMemsetAsync(ws + P_BYTES, 0, off - P_BYTES, stream);

    // d_out scratch (all dead before final_kernel rewrites d_out):
    //   [0, 128Mi):    v (bf16, [z][c][l]) written by qkv, read by ogemm
    //   [128Mi, +2Mi): Wbf (bf16 weights, fragment order) written by wcvt
    ushortT* vbuf = (ushortT*)d_out;
    ushortT* Wbf  = (ushortT*)((char*)d_out + ((size_t)134217728));
    float*   outf = (float*)d_out;

    wcvt_kernel<<<(4 * (W_EL / 8) + 255) / 256, 256, 0, stream>>>(Wq, Wk, Wv, Wo, Wbf);

    dim3 gq(LEN / LT, NB_B);   // (32, 64)
    qkv_kernel<<<gq, 256, 0, stream>>>(x, Wbf, bv, qsum, qmax, ksum, kmax, vbuf);
    attn_kernel<<<1, 256, 0, stream>>>(qsum, qmax, ksum, kmax, bq, bk, edge, bimp, attn);
    dim3 go(LEN / LT, BSZ);    // (32, 16): 512 blocks, 4 branches per block
    ogemm_kernel<<<go, 256, 0, stream>>>(vbuf, Wbf + (size_t)3 * W_EL, attn, bo, bnsum, bnss, outpre);
    bnfin_kernel<<<4, 256, 0, stream>>>(bnsum, bnss, gamma, beta, scl, shf);
    final_kernel<<<8192, 256, 0, stream>>>(outpre, x, scl, shf, outf);
}